// Round 16
// baseline (1321.903 us; speedup 1.0000x reference)
//
#include <hip/hip_runtime.h>
#include <math.h>

#define S_LEN 256
#define NCELL 8
#define HID 16
#define MEM 20
#define NB 4
#define NTHR 512
#define RSTR 2592   // ring batch stride in f16 (bank skew)
#define RP 80       // reduction row stride (floats): bank shift 16 -> 2-way

typedef _Float16 v8h __attribute__((ext_vector_type(8)));
typedef _Float16 v4h __attribute__((ext_vector_type(4)));
typedef float v4f __attribute__((ext_vector_type(4)));

__device__ __forceinline__ float sigm(float v) { return 1.0f / (1.0f + __expf(-v)); }
__device__ __forceinline__ float tanh_f(float v) { return 1.0f - 2.0f / (__expf(2.0f * v) + 1.0f); }
__device__ __forceinline__ float dot4(float4 a, float4 b) {
    return fmaf(a.x, b.x, fmaf(a.y, b.y, fmaf(a.z, b.z, a.w * b.w)));
}
__device__ __forceinline__ v4f mfma16(v8h a, v8h b, v4f c) {
    return __builtin_amdgcn_mfma_f32_16x16x32_f16(a, b, c, 0, 0, 0);
}

#define RING(b, s, k) ringH[(b) * RSTR + (s) * 128 + (k)]

// prep: W1F (163840 f16, MFMA A-frag order, verified R11) + WAF (16384 f16)
__global__ __launch_bounds__(256)
void prep_w(const float* __restrict__ W1, const float* __restrict__ W_hh,
            const float* __restrict__ W_ih, const float* __restrict__ b_ih,
            const float* __restrict__ b_hh, _Float16* __restrict__ W1F,
            _Float16* __restrict__ WAF) {
    int idx = blockIdx.x * 256 + threadIdx.x;
    if (idx < 163840) {
        int e = idx & 7, lane = (idx >> 3) & 63, jt = (idx >> 9) & 3, t = idx >> 11;
        int m = t >> 2, kc = t & 3;
        int j = jt * 16 + (lane & 15);
        int k = kc * 32 + (lane >> 4) * 8 + e;
        W1F[idx] = (_Float16)W1[j * 2580 + m * 129 + k];
    } else if (idx < 163840 + 16384) {
        int d = idx - 163840;
        int e = d & 7, lane = (d >> 3) & 63, gate = (d >> 9) & 3, c = d >> 11;
        int m = lane & 15, k = (lane >> 4) * 8 + e;
        int row = c * 64 + gate * 16 + m;
        float v = 0.f;
        if (k < 16) v = W_hh[row * 16 + k];
        else if (k == 16) v = W_ih[row];
        else if (k == 17) v = b_ih[row] + b_hh[row];
        WAF[d] = (_Float16)v;
    }
}

// R15 post-mortem: removing 4.5e7 conflict-cycles changed nothing -> all
// micro-resources have slack; the floor is the 3-barrier serial skeleton.
// R16: 2 barriers. All of old section 2a's outputs (m=0 term, errdot, theta,
// oS) are consumed only by wave 0 -> wave 0 computes them itself (m=0 = 16
// MFMA from LDS A-frags, kc-accumulated in registers; errdot/theta inline as
// in R11). Stream waves run m=1..19 immediately after B1 with the whole step
// as overlap window.
__global__ __attribute__((amdgpu_flat_work_group_size(NTHR, NTHR)))
void mmoe_kernel(const float* __restrict__ x, const float* __restrict__ pred0,
                 const float* __restrict__ gate0,
                 const float* __restrict__ W_ih, const float* __restrict__ W_hh,
                 const float* __restrict__ b_ih, const float* __restrict__ b_hh,
                 const float* __restrict__ W_o, const float* __restrict__ b_o,
                 const float* __restrict__ W1, const float* __restrict__ b1,
                 const float* __restrict__ W2, const float* __restrict__ b2,
                 const float* __restrict__ Wg, const float* __restrict__ bg,
                 const float* __restrict__ Wa_ih, const float* __restrict__ Wa_hh,
                 const float* __restrict__ ba_ih, const float* __restrict__ ba_hh,
                 const _Float16* __restrict__ W1F, const _Float16* __restrict__ WAF,
                 float* __restrict__ out)
{
    __shared__ __align__(16) _Float16 ringH[NB * RSTR];      // skewed ring (h rows)
    __shared__ __align__(16) _Float16 W10F_l[8192];          // m=0 A-frags (16 KB)
    __shared__ __align__(16) _Float16 ehH[NB][40];           // [eh(16)|x|1|0..] f16
    __shared__ float errS[NB][MEM];
    __shared__ __align__(16) float WaI[2][64 * 20], WaH[2][64 * 20];
    __shared__ float ba_l[2][64];
    __shared__ __align__(16) float W2_l[16 * 68];
    __shared__ float b2_l[16];
    __shared__ __align__(16) float Wg_l[8][16], Wo_l[8][16];
    __shared__ float bg_l[8], bo_l[8];
    __shared__ float Werr_l[MEM * 64];
    __shared__ float b1_l[64];
    __shared__ float xS[NB][S_LEN];
    __shared__ __align__(16) float ecS[NB][HID];
    __shared__ __align__(16) float nhS[NCELL][NB][HID];      // [c][b][h]: 2-way banks
    __shared__ __align__(16) float ncS[NCELL][NB][HID];
    __shared__ float oS[NB][NCELL], predS[NB], gateS[NB][NCELL];
    __shared__ __align__(16) float ahS[2][NB][HID], acS[2][NB][HID];
    __shared__ __align__(16) float e1S[NB][64], aiS[NB][HID];
    __shared__ __align__(16) float glog[NB][8];
    __shared__ __align__(16) float red[2][8][NB][RP];        // stream partials (pad 80)
    __shared__ __align__(16) float red0f[NB][RP];            // m=0 term (wave 0 only)

    const int tid = threadIdx.x;
    const int b0 = blockIdx.x * NB;
    const int lane = tid & 63, wv = tid >> 6;
    const int quad = lane >> 4, nn = lane & 15, bb4 = nn & 3;

    // ---- one-time staging ----
    for (int i = tid; i < 2048; i += NTHR) {
        int l = i >> 10, r = i & 1023, g = r >> 4, q = r & 15;
        WaI[l][g * 20 + q] = Wa_ih[i]; WaH[l][g * 20 + q] = Wa_hh[i];
    }
    for (int i = tid; i < 128; i += NTHR) { int l = i >> 6, g = i & 63; ba_l[l][g] = ba_ih[i] + ba_hh[i]; }
    for (int i = tid; i < 1024; i += NTHR) { int r = i >> 6, q = i & 63; W2_l[r * 68 + q] = W2[i]; }
    for (int i = tid; i < 1280; i += NTHR) { int m = i >> 6, j = i & 63; Werr_l[i] = W1[j * 2580 + m * 129 + 128]; }
    for (int i = tid; i < 8192; i += NTHR) W10F_l[i] = W1F[i];   // m=0 tiles
    if (tid < 64) b1_l[tid] = b1[tid];
    if (tid < 16) b2_l[tid] = b2[tid];
    if (tid < 128) { int c = tid >> 4, h = tid & 15; Wg_l[c][h] = Wg[tid]; Wo_l[c][h] = W_o[tid]; }
    if (tid < 8) { bg_l[tid] = bg[tid]; bo_l[tid] = b_o[tid]; }
    for (int i = tid; i < NB * S_LEN; i += NTHR) { int b = i >> 8, s = i & 255; xS[b][s] = x[(b0 + b) * S_LEN + s]; }
    for (int i = tid; i < NB * RSTR; i += NTHR) ringH[i] = (_Float16)0.0f;
    for (int i = tid; i < 2 * 8 * NB * RP; i += NTHR) ((float*)red)[i] = 0.0f;
    if (tid < NB * 40) {
        int n = tid / 40, k = tid % 40;
        float v = 0.f;
        if (k == 16) v = x[(b0 + n) * S_LEN + 0];
        else if (k == 17) v = 1.0f;
        ehH[n][k] = (_Float16)v;
    }
    if (tid < NB * MEM) { int b = tid / MEM, m = tid % MEM; errS[b][m] = 0.5f; }
    if (tid < NB * HID) {
        int b = tid >> 4, h = tid & 15;
        ecS[b][h] = 0.f;
        ahS[0][b][h] = 0.f; ahS[1][b][h] = 0.f;
        acS[0][b][h] = 0.f; acS[1][b][h] = 0.f;
    }
    if (tid < NB) predS[tid] = pred0[b0 + tid];
    if (tid < NB * NCELL) { int b = tid >> 3, c = tid & 7; gateS[b][c] = gate0[(b0 + b) * NCELL + c]; }

    // ---- loop-invariant register A-frags (expert cell = wv) ----
    const v8h* WA = (const v8h*)WAF;
    v8h aI = WA[(wv * 4 + 0) * 64 + lane];
    v8h aF = WA[(wv * 4 + 1) * 64 + lane];
    v8h aG = WA[(wv * 4 + 2) * 64 + lane];
    v8h aO = WA[(wv * 4 + 3) * 64 + lane];
    const v8h* Wb = (const v8h*)W1F;
    const v8h* WL = (const v8h*)W10F_l;
    __syncthreads();

    int head = 0;
    #pragma unroll 1
    for (int t = 0; t < S_LEN; ++t) {
        head = (head == 0) ? (MEM - 1) : (head - 1);
        const int par = t & 1, np = par ^ 1;

        // ---- Section 1: phase A via MFMA (wave = cell wv) ----
        {
            v8h bfrag = *(const v8h*)&ehH[bb4][quad * 8];
            v4f z4 = {0.f, 0.f, 0.f, 0.f};
            v4f zi = mfma16(aI, bfrag, z4);
            v4f zf = mfma16(aF, bfrag, z4);
            v4f zg = mfma16(aG, bfrag, z4);
            v4f zo = mfma16(aO, bfrag, z4);
            if (nn < 4) {
                int b = nn, c = wv;
                v4f hv4, cv4; v4h hr;
                #pragma unroll
                for (int r = 0; r < 4; ++r) {
                    int h = quad * 4 + r;
                    float cc = ecS[b][h];
                    float c2 = sigm(zf[r]) * cc + sigm(zi[r]) * tanh_f(zg[r]);
                    float hv = sigm(zo[r]) * tanh_f(c2);
                    hv4[r] = hv; cv4[r] = c2; hr[r] = (_Float16)hv;
                }
                *(v4f*)&nhS[c][b][quad * 4] = hv4;
                *(v4f*)&ncS[c][b][quad * 4] = cv4;
                *(v4h*)&RING(b, head, c * 16 + quad * 4) = hr;
            }
            if (tid < NB) errS[tid][head] = xS[tid][t] - predS[tid];
        }
        __syncthreads();   // B1  (only barrier inside the step besides B3)

        if (wv >= 1) {
            // ---- stream m=1..19 (waves 1-7, depth-1) -> red[np][wv] ----
            int kt = (wv - 1) * 11;
            int ktEnd = kt + 11; if (ktEnd > 76) ktEnd = 76;
            v4f c0 = {0.f,0.f,0.f,0.f}, c1 = {0.f,0.f,0.f,0.f};
            v4f c2 = {0.f,0.f,0.f,0.f}, c3 = {0.f,0.f,0.f,0.f};
            size_t tb = (size_t)(4 + kt) * 256 + lane;
            v8h pA0 = Wb[tb], pA1 = Wb[tb + 64], pA2 = Wb[tb + 128], pA3 = Wb[tb + 192];
            int m0 = 1 + (kt >> 2), kc0 = kt & 3;
            int s0 = head + m0 - 1; if (s0 >= MEM) s0 -= MEM;
            v8h pB = *(const v8h*)&RING(bb4, s0, kc0 * 32 + quad * 8);
            #pragma unroll 1
            for (; kt < ktEnd; ++kt) {
                v8h A0 = pA0, A1 = pA1, A2 = pA2, A3 = pA3, B = pB;
                int kn = kt + 1;
                if (kn < ktEnd) {
                    size_t tn = (size_t)(4 + kn) * 256 + lane;
                    pA0 = Wb[tn]; pA1 = Wb[tn + 64]; pA2 = Wb[tn + 128]; pA3 = Wb[tn + 192];
                    int mn = 1 + (kn >> 2), kcn = kn & 3;
                    int sn = head + mn - 1; if (sn >= MEM) sn -= MEM;
                    pB = *(const v8h*)&RING(bb4, sn, kcn * 32 + quad * 8);
                }
                c0 = mfma16(A0, B, c0);
                c1 = mfma16(A1, B, c1);
                c2 = mfma16(A2, B, c2);
                c3 = mfma16(A3, B, c3);
            }
            if (nn < 4) {
                *(v4f*)&red[np][wv][nn][ 0 + quad * 4] = c0;
                *(v4f*)&red[np][wv][nn][16 + quad * 4] = c1;
                *(v4f*)&red[np][wv][nn][32 + quad * 4] = c2;
                *(v4f*)&red[np][wv][nn][48 + quad * 4] = c3;
            }
        } else {
            // ---- wave 0 mega-tail ----
            // 1) m=0 term: 16 MFMA, kc-accumulated in registers
            v4f z = {0.f, 0.f, 0.f, 0.f};
            v4f a0 = z, a1 = z, a2 = z, a3 = z;
            #pragma unroll
            for (int kc = 0; kc < 4; ++kc) {
                v8h bf = *(const v8h*)&RING(bb4, head, kc * 32 + quad * 8);
                a0 = mfma16(WL[(kc * 4 + 0) * 64 + lane], bf, a0);
                a1 = mfma16(WL[(kc * 4 + 1) * 64 + lane], bf, a1);
                a2 = mfma16(WL[(kc * 4 + 2) * 64 + lane], bf, a2);
                a3 = mfma16(WL[(kc * 4 + 3) * 64 + lane], bf, a3);
            }
            // 2) E1P: prev-step stream partials + bias
            float v0 = b1_l[lane], v1 = v0, v2 = v0, v3 = v0;
            #pragma unroll
            for (int g = 1; g < 8; ++g) {
                v0 += red[par][g][0][lane];
                v1 += red[par][g][1][lane];
                v2 += red[par][g][2][lane];
                v3 += red[par][g][3][lane];
            }
            // 3) error-column dot (f32)
            float ed0 = 0.f, ed1 = 0.f, ed2 = 0.f, ed3 = 0.f;
            {
                int sl = head;
                #pragma unroll
                for (int m = 0; m < MEM; ++m) {
                    float w = Werr_l[m * 64 + lane];
                    ed0 = fmaf(w, errS[0][sl], ed0);
                    ed1 = fmaf(w, errS[1][sl], ed1);
                    ed2 = fmaf(w, errS[2][sl], ed2);
                    ed3 = fmaf(w, errS[3][sl], ed3);
                    ++sl; if (sl >= MEM) sl = 0;
                }
            }
            // 4) m=0 C-layout -> per-lane j layout via LDS (intra-wave)
            if (nn < 4) {
                *(v4f*)&red0f[nn][ 0 + quad * 4] = a0;
                *(v4f*)&red0f[nn][16 + quad * 4] = a1;
                *(v4f*)&red0f[nn][32 + quad * 4] = a2;
                *(v4f*)&red0f[nn][48 + quad * 4] = a3;
            }
            // 5) E1F + relu
            e1S[0][lane] = fmaxf(v0 + ed0 + red0f[0][lane], 0.f);
            e1S[1][lane] = fmaxf(v1 + ed1 + red0f[1][lane], 0.f);
            e1S[2][lane] = fmaxf(v2 + ed2 + red0f[2][lane], 0.f);
            e1S[3][lane] = fmaxf(v3 + ed3 + red0f[3][lane], 0.f);
            // 6) expert heads o (lanes 0-31)
            const int j = lane;
            if (j < 32) {
                int bb = j >> 3, c = j & 7;
                const float4* np_ = (const float4*)&nhS[c][bb][0];
                const float4* wp = (const float4*)&Wo_l[c][0];
                float s = bo_l[c];
                #pragma unroll
                for (int q4 = 0; q4 < 4; ++q4) s += dot4(np_[q4], wp[q4]);
                oS[bb][c] = s;
            }
            // 7) ai: 64 lanes = 4b x 16i
            {
                int bb = j >> 4, i = j & 15;
                const float4* epq = (const float4*)&e1S[bb][0];
                float s = b2_l[i];
                #pragma unroll
                for (int q = 0; q < 16; ++q) s += dot4(*(const float4*)&W2_l[i * 68 + q * 4], epq[q]);
                aiS[bb][i] = fmaxf(s, 0.f);
            }
            // 8) agent LSTM x2: 4b x 16h
            #pragma unroll
            for (int l = 0; l < 2; ++l) {
                int bb = j >> 4, h = j & 15;
                const float4* ip = (l == 0) ? (const float4*)&aiS[bb][0]
                                            : (const float4*)&ahS[0][bb][0];
                const float4* hp = (const float4*)&ahS[l][bb][0];
                float4 i0 = ip[0], i1 = ip[1], i2 = ip[2], i3 = ip[3];
                float4 h0 = hp[0], h1 = hp[1], h2v = hp[2], h3 = hp[3];
                float zg[4];
                #pragma unroll
                for (int gi = 0; gi < 4; ++gi) {
                    int g = gi * 16 + h;
                    const float* wi = &WaI[l][g * 20];
                    const float* wh = &WaH[l][g * 20];
                    float zz = ba_l[l][g];
                    zz += dot4(i0, *(const float4*)&wi[0]) + dot4(i1, *(const float4*)&wi[4])
                        + dot4(i2, *(const float4*)&wi[8]) + dot4(i3, *(const float4*)&wi[12]);
                    zz += dot4(h0, *(const float4*)&wh[0]) + dot4(h1, *(const float4*)&wh[4])
                        + dot4(h2v, *(const float4*)&wh[8]) + dot4(h3, *(const float4*)&wh[12]);
                    zg[gi] = zz;
                }
                float c2 = sigm(zg[1]) * acS[l][bb][h] + sigm(zg[0]) * tanh_f(zg[2]);
                acS[l][bb][h] = c2;
                ahS[l][bb][h] = sigm(zg[3]) * tanh_f(c2);
            }
            // 9) gate logits + softmax + theta blend (lanes 0-31)
            if (j < 32) {
                int bb = j >> 3, c = j & 7;
                const float4* hp = (const float4*)&ahS[1][bb][0];
                const float4* wg = (const float4*)&Wg_l[c][0];
                float s = bg_l[c];
                #pragma unroll
                for (int q = 0; q < 4; ++q) s += dot4(wg[q], hp[q]);
                glog[bb][c] = s;
                float4 ga = *(const float4*)&glog[bb][0];
                float4 gb = *(const float4*)&glog[bb][4];
                float mx = fmaxf(fmaxf(fmaxf(ga.x, ga.y), fmaxf(ga.z, ga.w)),
                                 fmaxf(fmaxf(gb.x, gb.y), fmaxf(gb.z, gb.w)));
                float sum = __expf(ga.x - mx) + __expf(ga.y - mx) + __expf(ga.z - mx) + __expf(ga.w - mx)
                          + __expf(gb.x - mx) + __expf(gb.y - mx) + __expf(gb.z - mx) + __expf(gb.w - mx);
                float p = __expf(s - mx) / sum;
                float th = 0.f;
                #pragma unroll
                for (int m = 0; m < 10; ++m) {
                    int sl = head + m; if (sl >= MEM) sl -= MEM;
                    th += fabsf(errS[bb][sl]);
                }
                th *= 0.25f;
                th = fminf(fmaxf(th, 0.f), 1.f);
                gateS[bb][c] = p * th + gateS[bb][c] * (1.f - th);
            }
            // 10) combine -> ehH + ecS
            {
                int bb = j >> 4, h = j & 15;
                float se = 0.f, sc = 0.f;
                #pragma unroll
                for (int c = 0; c < 8; ++c) {
                    float g = gateS[bb][c];
                    se = fmaf(g, nhS[c][bb][h], se);
                    sc = fmaf(g, ncS[c][bb][h], sc);
                }
                ehH[bb][h] = (_Float16)se;
                ecS[bb][h] = sc;
            }
            // 11) pred + output + next x slot
            if (j < NB) {
                float s = 0.f;
                #pragma unroll
                for (int c = 0; c < 8; ++c) s = fmaf(gateS[j][c], oS[j][c], s);
                predS[j] = s;
                out[(b0 + j) * S_LEN + t] = s;
                ehH[j][16] = (_Float16)((t + 1 < S_LEN) ? xS[j][t + 1] : 0.f);
            }
        }
        __syncthreads();   // B3
    }
}

extern "C" void kernel_launch(void* const* d_in, const int* in_sizes, int n_in,
                              void* d_out, int out_size, void* d_ws, size_t ws_size,
                              hipStream_t stream) {
    const float* xp    = (const float*)d_in[0];
    const float* pred0 = (const float*)d_in[1];
    const float* gate0 = (const float*)d_in[2];
    const float* W_ih  = (const float*)d_in[3];
    const float* W_hh  = (const float*)d_in[4];
    const float* b_ih  = (const float*)d_in[5];
    const float* b_hh  = (const float*)d_in[6];
    const float* W_o   = (const float*)d_in[7];
    const float* b_o   = (const float*)d_in[8];
    const float* W1    = (const float*)d_in[9];
    const float* b1    = (const float*)d_in[10];
    const float* W2    = (const float*)d_in[11];
    const float* b2    = (const float*)d_in[12];
    const float* Wg    = (const float*)d_in[13];
    const float* bg    = (const float*)d_in[14];
    const float* Wa_ih = (const float*)d_in[15];
    const float* Wa_hh = (const float*)d_in[16];
    const float* ba_ih = (const float*)d_in[17];
    const float* ba_hh = (const float*)d_in[18];
    _Float16* W1F = (_Float16*)d_ws;                 // 320 KB
    _Float16* WAF = W1F + 163840;                    // +32 KB expert A-frags

    prep_w<<<(163840 + 16384 + 255) / 256, 256, 0, stream>>>(
        W1, W_hh, W_ih, b_ih, b_hh, W1F, WAF);
    mmoe_kernel<<<512 / NB, NTHR, 0, stream>>>(
        xp, pred0, gate0, W_ih, W_hh, b_ih, b_hh, W_o, b_o,
        W1, b1, W2, b2, Wg, bg, Wa_ih, Wa_hh, ba_ih, ba_hh,
        W1F, WAF, (float*)d_out);
}

// Round 17
// 1271.675 us; speedup vs baseline: 1.0395x; 1.0395x over previous
//
#include <hip/hip_runtime.h>
#include <math.h>

#define S_LEN 256
#define NCELL 8
#define HID 16
#define MEM 20
#define NB 4
#define NTHR 512
#define RSTR 2592   // ring batch stride in f16 (bank skew)
#define RP 80       // reduction row stride (floats): bank shift 16 -> 2-way

typedef _Float16 v8h __attribute__((ext_vector_type(8)));
typedef _Float16 v4h __attribute__((ext_vector_type(4)));
typedef float v4f __attribute__((ext_vector_type(4)));

__device__ __forceinline__ float sigm(float v) { return 1.0f / (1.0f + __expf(-v)); }
__device__ __forceinline__ float tanh_f(float v) { return 1.0f - 2.0f / (__expf(2.0f * v) + 1.0f); }
__device__ __forceinline__ float dot4(float4 a, float4 b) {
    return fmaf(a.x, b.x, fmaf(a.y, b.y, fmaf(a.z, b.z, a.w * b.w)));
}
__device__ __forceinline__ v4f mfma16(v8h a, v8h b, v4f c) {
    return __builtin_amdgcn_mfma_f32_16x16x32_f16(a, b, c, 0, 0, 0);
}

#define RING(b, s, k) ringH[(b) * RSTR + (s) * 128 + (k)]

// prep: W1F (163840 f16, A-frag order, verified R11) + WAF (16384, expert
// cells) + W2F (1024, W2 as 2 K-tiles) + WAGF (4096, agent [Wa_ih|Wa_hh]
// K=32 A-frags, 2 layers x 4 gate-tiles).
__global__ __launch_bounds__(256)
void prep_w(const float* __restrict__ W1, const float* __restrict__ W_hh,
            const float* __restrict__ W_ih, const float* __restrict__ b_ih,
            const float* __restrict__ b_hh, const float* __restrict__ W2,
            const float* __restrict__ Wa_ih, const float* __restrict__ Wa_hh,
            _Float16* __restrict__ W1F, _Float16* __restrict__ WAF,
            _Float16* __restrict__ W2F, _Float16* __restrict__ WAGF) {
    int idx = blockIdx.x * 256 + threadIdx.x;
    if (idx < 163840) {
        int e = idx & 7, lane = (idx >> 3) & 63, jt = (idx >> 9) & 3, t = idx >> 11;
        int m = t >> 2, kc = t & 3;
        int j = jt * 16 + (lane & 15);
        int k = kc * 32 + (lane >> 4) * 8 + e;
        W1F[idx] = (_Float16)W1[j * 2580 + m * 129 + k];
    } else if (idx < 163840 + 16384) {
        int d = idx - 163840;
        int e = d & 7, lane = (d >> 3) & 63, gate = (d >> 9) & 3, c = d >> 11;
        int m = lane & 15, k = (lane >> 4) * 8 + e;
        int row = c * 64 + gate * 16 + m;
        float v = 0.f;
        if (k < 16) v = W_hh[row * 16 + k];
        else if (k == 16) v = W_ih[row];
        else if (k == 17) v = b_ih[row] + b_hh[row];
        WAF[d] = (_Float16)v;
    } else if (idx < 163840 + 16384 + 1024) {
        int d = idx - 163840 - 16384;
        int e = d & 7, lane = (d >> 3) & 63, kc = d >> 9;
        int i = lane & 15, k = kc * 32 + (lane >> 4) * 8 + e;
        W2F[d] = (_Float16)W2[i * 64 + k];
    } else if (idx < 163840 + 16384 + 1024 + 4096) {
        int d = idx - 163840 - 16384 - 1024;
        int e = d & 7, lane = (d >> 3) & 63, jt = (d >> 9) & 3, l = d >> 11;
        int g = jt * 16 + (lane & 15);
        int k = (lane >> 4) * 8 + e;
        float v = (k < 16) ? Wa_ih[(l * 64 + g) * 16 + k]
                           : Wa_hh[(l * 64 + g) * 16 + (k - 16)];
        WAGF[d] = (_Float16)v;
    }
}

// R16 post-mortem: barrier count not binding; wave-0 serial chain carries real
// weight (+700 chain cyc -> +40us). R17 = R15 base + chain diet: ai = 2
// chained MFMA (K=64), each agent LSTM layer = 4 MFMA (A=[Wa_ih|Wa_hh],
// K=32 = [inp|h]); C-layout puts (batch,h) on lanes like phase A ->
// activations in registers. Wave-0 code ~3x smaller.
#define E1P(BB, V) { \
    V = b1_l[lane] \
      + red[par][1][BB][lane] + red[par][2][BB][lane] + red[par][3][BB][lane] \
      + red[par][4][BB][lane] + red[par][5][BB][lane] + red[par][6][BB][lane] \
      + red[par][7][BB][lane]; }

__global__ __attribute__((amdgpu_flat_work_group_size(NTHR, NTHR)))
void mmoe_kernel(const float* __restrict__ x, const float* __restrict__ pred0,
                 const float* __restrict__ gate0,
                 const float* __restrict__ W_ih, const float* __restrict__ W_hh,
                 const float* __restrict__ b_ih, const float* __restrict__ b_hh,
                 const float* __restrict__ W_o, const float* __restrict__ b_o,
                 const float* __restrict__ W1, const float* __restrict__ b1,
                 const float* __restrict__ W2, const float* __restrict__ b2,
                 const float* __restrict__ Wg, const float* __restrict__ bg,
                 const float* __restrict__ Wa_ih, const float* __restrict__ Wa_hh,
                 const float* __restrict__ ba_ih, const float* __restrict__ ba_hh,
                 const _Float16* __restrict__ W1F, const _Float16* __restrict__ WAF,
                 const _Float16* __restrict__ W2F, const _Float16* __restrict__ WAGF,
                 float* __restrict__ out)
{
    __shared__ __align__(16) _Float16 ringH[NB * RSTR];      // skewed ring (h rows)
    __shared__ __align__(16) _Float16 ehH[NB][40];           // [eh(16)|x|1|0..] f16
    __shared__ __align__(16) _Float16 W2F_l[2 * 512];        // ai A-frags
    __shared__ __align__(16) _Float16 WaG_l[2 * 4 * 512];    // agent A-frags
    __shared__ __align__(16) _Float16 e1B[NB][64];           // e1 f16 (ai B operand)
    __shared__ __align__(16) _Float16 agB0[NB][32];          // [inp|ah0] layer-0 B
    __shared__ __align__(16) _Float16 agB1[NB][32];          // [ah0|ah1] layer-1 B
    __shared__ float errS[NB][MEM];
    __shared__ float ba_l[2][64];
    __shared__ float b2_l[16];
    __shared__ __align__(16) float Wg_l[8][16], Wo_l[8][16];
    __shared__ float bg_l[8], bo_l[8];
    __shared__ float Werr_l[MEM * 64];
    __shared__ float b1_l[64];
    __shared__ float xS[NB][S_LEN];
    __shared__ __align__(16) float ecS[NB][HID];
    __shared__ __align__(16) float nhS[NCELL][NB][HID];      // [c][b][h]: 2-way banks
    __shared__ __align__(16) float ncS[NCELL][NB][HID];
    __shared__ float oS[NB][NCELL], predS[NB], gateS[NB][NCELL];
    __shared__ __align__(16) float acS[2][NB][HID];
    __shared__ __align__(16) float ah1S[NB][HID];            // layer-1 h, f32 (gate dot)
    __shared__ __align__(16) float glog[NB][8];
    __shared__ __align__(16) float red[2][8][NB][RP];        // stream partials (pad 80)
    __shared__ __align__(16) float red0[4][NB][RP];          // m=0 term (pad 80)
    __shared__ float errdotS[NB][64];
    __shared__ float thS[NB];

    const int tid = threadIdx.x;
    const int b0 = blockIdx.x * NB;
    const int lane = tid & 63, wv = tid >> 6;
    const int quad = lane >> 4, nn = lane & 15, bb4 = nn & 3;

    // ---- one-time staging ----
    for (int i = tid; i < 128; i += NTHR) { int l = i >> 6, g = i & 63; ba_l[l][g] = ba_ih[i] + ba_hh[i]; }
    for (int i = tid; i < 1024; i += NTHR) W2F_l[i] = W2F[i];
    for (int i = tid; i < 4096; i += NTHR) WaG_l[i] = WAGF[i];
    for (int i = tid; i < 1280; i += NTHR) { int m = i >> 6, j = i & 63; Werr_l[i] = W1[j * 2580 + m * 129 + 128]; }
    if (tid < 64) b1_l[tid] = b1[tid];
    if (tid < 16) b2_l[tid] = b2[tid];
    if (tid < 128) { int c = tid >> 4, h = tid & 15; Wg_l[c][h] = Wg[tid]; Wo_l[c][h] = W_o[tid]; }
    if (tid < 8) { bg_l[tid] = bg[tid]; bo_l[tid] = b_o[tid]; }
    for (int i = tid; i < NB * S_LEN; i += NTHR) { int b = i >> 8, s = i & 255; xS[b][s] = x[(b0 + b) * S_LEN + s]; }
    for (int i = tid; i < NB * RSTR; i += NTHR) ringH[i] = (_Float16)0.0f;
    for (int i = tid; i < 2 * 8 * NB * RP; i += NTHR) ((float*)red)[i] = 0.0f;
    for (int i = tid; i < NB * 32; i += NTHR) { ((_Float16*)agB0)[i] = (_Float16)0.0f; ((_Float16*)agB1)[i] = (_Float16)0.0f; }
    if (tid < NB * 40) {
        int n = tid / 40, k = tid % 40;
        float v = 0.f;
        if (k == 16) v = x[(b0 + n) * S_LEN + 0];
        else if (k == 17) v = 1.0f;
        ehH[n][k] = (_Float16)v;
    }
    if (tid < NB * MEM) { int b = tid / MEM, m = tid % MEM; errS[b][m] = 0.5f; }
    if (tid < NB * HID) {
        int b = tid >> 4, h = tid & 15;
        ecS[b][h] = 0.f;
        acS[0][b][h] = 0.f; acS[1][b][h] = 0.f;
        ah1S[b][h] = 0.f;
    }
    if (tid < NB) predS[tid] = pred0[b0 + tid];
    if (tid < NB * NCELL) { int b = tid >> 3, c = tid & 7; gateS[b][c] = gate0[(b0 + b) * NCELL + c]; }

    // ---- loop-invariant register A-frags ----
    const v8h* WA = (const v8h*)WAF;
    v8h aI = WA[(wv * 4 + 0) * 64 + lane];
    v8h aF = WA[(wv * 4 + 1) * 64 + lane];
    v8h aG = WA[(wv * 4 + 2) * 64 + lane];
    v8h aO = WA[(wv * 4 + 3) * 64 + lane];
    const v8h* Wb = (const v8h*)W1F;
    const int kcW = wv >> 1, jt0W = (wv & 1) * 2;
    v8h m0A = Wb[(size_t)(kcW * 4 + jt0W) * 64 + lane];
    v8h m0B = Wb[(size_t)(kcW * 4 + jt0W + 1) * 64 + lane];
    const v8h* W2Fv = (const v8h*)W2F_l;
    const v8h* WaGv = (const v8h*)WaG_l;
    __syncthreads();
    // wave-0 loop-invariant bias vector for ai MFMA C-init
    v4f b2v;
    #pragma unroll
    for (int r = 0; r < 4; ++r) b2v[r] = b2_l[quad * 4 + r];

    int head = 0;
    #pragma unroll 1
    for (int t = 0; t < S_LEN; ++t) {
        head = (head == 0) ? (MEM - 1) : (head - 1);
        const int par = t & 1, np = par ^ 1;
        float v0, v1, v2, v3;

        // ---- Section 1: phase A via MFMA (wave = cell wv) ----
        {
            v8h bfrag = *(const v8h*)&ehH[bb4][quad * 8];
            v4f z4 = {0.f, 0.f, 0.f, 0.f};
            v4f zi = mfma16(aI, bfrag, z4);
            v4f zf = mfma16(aF, bfrag, z4);
            v4f zg = mfma16(aG, bfrag, z4);
            v4f zo = mfma16(aO, bfrag, z4);
            if (nn < 4) {
                int b = nn, c = wv;
                v4f hv4, cv4; v4h hr;
                #pragma unroll
                for (int r = 0; r < 4; ++r) {
                    int h = quad * 4 + r;
                    float cc = ecS[b][h];
                    float c2 = sigm(zf[r]) * cc + sigm(zi[r]) * tanh_f(zg[r]);
                    float hv = sigm(zo[r]) * tanh_f(c2);
                    hv4[r] = hv; cv4[r] = c2; hr[r] = (_Float16)hv;
                }
                *(v4f*)&nhS[c][b][quad * 4] = hv4;
                *(v4f*)&ncS[c][b][quad * 4] = cv4;
                *(v4h*)&RING(b, head, c * 16 + quad * 4) = hr;
            }
            if (tid < NB) errS[tid][head] = xS[tid][t] - predS[tid];
        }
        __syncthreads();   // B1

        // ---- Section 2a: m=0 MFMA (register A-frags) + parallel tail-prep ----
        {
            v8h bfrag = *(const v8h*)&RING(bb4, head, kcW * 32 + quad * 8);
            v4f z = {0.f, 0.f, 0.f, 0.f};
            v4f c0 = mfma16(m0A, bfrag, z);
            v4f c1 = mfma16(m0B, bfrag, z);
            if (nn < 4) {
                *(v4f*)&red0[kcW][nn][jt0W * 16 + quad * 4] = c0;
                *(v4f*)&red0[kcW][nn][(jt0W + 1) * 16 + quad * 4] = c1;
            }
            if (wv == 0) {
                E1P(0, v0) E1P(1, v1) E1P(2, v2) E1P(3, v3)
            } else if (wv == 1) {
                if (lane < 32) {
                    int bb = lane >> 3, c = lane & 7;
                    const float4* np_ = (const float4*)&nhS[c][bb][0];
                    const float4* wp = (const float4*)&Wo_l[c][0];
                    float s = bo_l[c];
                    #pragma unroll
                    for (int q4 = 0; q4 < 4; ++q4) s += dot4(np_[q4], wp[q4]);
                    oS[bb][c] = s;
                }
            } else if (wv == 2) {
                if (lane < NB) {
                    float th = 0.f;
                    #pragma unroll
                    for (int m = 0; m < 10; ++m) {
                        int sl = head + m; if (sl >= MEM) sl -= MEM;
                        th += fabsf(errS[lane][sl]);
                    }
                    th *= 0.25f;
                    thS[lane] = fminf(fmaxf(th, 0.f), 1.f);
                }
            } else if (wv >= 3 && wv < 7) {
                int bb = wv - 3;
                float s = 0.f;
                int sl = head;
                #pragma unroll
                for (int m = 0; m < MEM; ++m) {
                    s = fmaf(Werr_l[m * 64 + lane], errS[bb][sl], s);
                    ++sl; if (sl >= MEM) sl = 0;
                }
                errdotS[bb][lane] = s;
            }
        }
        __syncthreads();   // B2

        // ---- Section 2b: stream m=1..19 (waves 1-7) || MFMA tail (wave 0) ----
        if (wv >= 1) {
            int kt = (wv - 1) * 11;
            int ktEnd = kt + 11; if (ktEnd > 76) ktEnd = 76;
            v4f c0 = {0.f,0.f,0.f,0.f}, c1 = {0.f,0.f,0.f,0.f};
            v4f c2 = {0.f,0.f,0.f,0.f}, c3 = {0.f,0.f,0.f,0.f};
            size_t tb = (size_t)(4 + kt) * 256 + lane;
            v8h pA0 = Wb[tb], pA1 = Wb[tb + 64], pA2 = Wb[tb + 128], pA3 = Wb[tb + 192];
            int m0 = 1 + (kt >> 2), kc0 = kt & 3;
            int s0 = head + m0 - 1; if (s0 >= MEM) s0 -= MEM;
            v8h pB = *(const v8h*)&RING(bb4, s0, kc0 * 32 + quad * 8);
            #pragma unroll 1
            for (; kt < ktEnd; ++kt) {
                v8h A0 = pA0, A1 = pA1, A2 = pA2, A3 = pA3, B = pB;
                int kn = kt + 1;
                if (kn < ktEnd) {
                    size_t tn = (size_t)(4 + kn) * 256 + lane;
                    pA0 = Wb[tn]; pA1 = Wb[tn + 64]; pA2 = Wb[tn + 128]; pA3 = Wb[tn + 192];
                    int mn = 1 + (kn >> 2), kcn = kn & 3;
                    int sn = head + mn - 1; if (sn >= MEM) sn -= MEM;
                    pB = *(const v8h*)&RING(bb4, sn, kcn * 32 + quad * 8);
                }
                c0 = mfma16(A0, B, c0);
                c1 = mfma16(A1, B, c1);
                c2 = mfma16(A2, B, c2);
                c3 = mfma16(A3, B, c3);
            }
            if (nn < 4) {
                *(v4f*)&red[np][wv][nn][ 0 + quad * 4] = c0;
                *(v4f*)&red[np][wv][nn][16 + quad * 4] = c1;
                *(v4f*)&red[np][wv][nn][32 + quad * 4] = c2;
                *(v4f*)&red[np][wv][nn][48 + quad * 4] = c3;
            }
        } else {
            // ---- wave-0 MFMA tail ----
            // E1F -> e1B f16
            {
                float r0 = fmaxf(v0 + errdotS[0][lane]
                       + red0[0][0][lane] + red0[1][0][lane] + red0[2][0][lane] + red0[3][0][lane], 0.f);
                float r1 = fmaxf(v1 + errdotS[1][lane]
                       + red0[0][1][lane] + red0[1][1][lane] + red0[2][1][lane] + red0[3][1][lane], 0.f);
                float r2 = fmaxf(v2 + errdotS[2][lane]
                       + red0[0][2][lane] + red0[1][2][lane] + red0[2][2][lane] + red0[3][2][lane], 0.f);
                float r3 = fmaxf(v3 + errdotS[3][lane]
                       + red0[0][3][lane] + red0[1][3][lane] + red0[2][3][lane] + red0[3][3][lane], 0.f);
                e1B[0][lane] = (_Float16)r0;
                e1B[1][lane] = (_Float16)r1;
                e1B[2][lane] = (_Float16)r2;
                e1B[3][lane] = (_Float16)r3;
            }
            // ai = relu(W2 . e1 + b2): 2 chained MFMA, write agB0 inp slots
            {
                v8h bk0 = *(const v8h*)&e1B[bb4][quad * 8];
                v8h bk1 = *(const v8h*)&e1B[bb4][32 + quad * 8];
                v4f cai = mfma16(W2Fv[lane], bk0, b2v);
                cai = mfma16(W2Fv[64 + lane], bk1, cai);
                if (nn < 4) {
                    v4h av;
                    #pragma unroll
                    for (int r = 0; r < 4; ++r) av[r] = (_Float16)fmaxf(cai[r], 0.f);
                    *(v4h*)&agB0[nn][quad * 4] = av;
                }
            }
            // agent layer 0: 4 MFMA; activations on lanes nn<4
            {
                v8h bf = *(const v8h*)&agB0[bb4][quad * 8];
                v4f z4 = {0.f, 0.f, 0.f, 0.f};
                v4f zi = mfma16(WaGv[0 * 64 + lane], bf, z4);
                v4f zf = mfma16(WaGv[1 * 64 + lane], bf, z4);
                v4f zg = mfma16(WaGv[2 * 64 + lane], bf, z4);
                v4f zo = mfma16(WaGv[3 * 64 + lane], bf, z4);
                if (nn < 4) {
                    v4h hr;
                    #pragma unroll
                    for (int r = 0; r < 4; ++r) {
                        int g = quad * 4 + r;
                        float zi_ = zi[r] + ba_l[0][g], zf_ = zf[r] + ba_l[0][16 + g];
                        float zg_ = zg[r] + ba_l[0][32 + g], zo_ = zo[r] + ba_l[0][48 + g];
                        float c2 = sigm(zf_) * acS[0][nn][g] + sigm(zi_) * tanh_f(zg_);
                        acS[0][nn][g] = c2;
                        hr[r] = (_Float16)(sigm(zo_) * tanh_f(c2));
                    }
                    *(v4h*)&agB1[nn][quad * 4] = hr;       // layer-1 input (this step)
                    *(v4h*)&agB0[nn][16 + quad * 4] = hr;  // layer-0 hidden (next step)
                }
            }
            // agent layer 1: 4 MFMA; activations + ah1S f32
            {
                v8h bf = *(const v8h*)&agB1[bb4][quad * 8];
                v4f z4 = {0.f, 0.f, 0.f, 0.f};
                v4f zi = mfma16(WaGv[4 * 64 + lane], bf, z4);
                v4f zf = mfma16(WaGv[5 * 64 + lane], bf, z4);
                v4f zg = mfma16(WaGv[6 * 64 + lane], bf, z4);
                v4f zo = mfma16(WaGv[7 * 64 + lane], bf, z4);
                if (nn < 4) {
                    v4h hr; v4f hf;
                    #pragma unroll
                    for (int r = 0; r < 4; ++r) {
                        int g = quad * 4 + r;
                        float zi_ = zi[r] + ba_l[1][g], zf_ = zf[r] + ba_l[1][16 + g];
                        float zg_ = zg[r] + ba_l[1][32 + g], zo_ = zo[r] + ba_l[1][48 + g];
                        float c2 = sigm(zf_) * acS[1][nn][g] + sigm(zi_) * tanh_f(zg_);
                        acS[1][nn][g] = c2;
                        float hv = sigm(zo_) * tanh_f(c2);
                        hf[r] = hv; hr[r] = (_Float16)hv;
                    }
                    *(v4f*)&ah1S[nn][quad * 4] = hf;
                    *(v4h*)&agB1[nn][16 + quad * 4] = hr;  // layer-1 hidden (next step)
                }
            }
            const int j = lane;
            // gate logits + softmax + theta blend (lanes 0-31)
            if (j < 32) {
                int bb = j >> 3, c = j & 7;
                const float4* hp = (const float4*)&ah1S[bb][0];
                const float4* wg = (const float4*)&Wg_l[c][0];
                float s = bg_l[c];
                #pragma unroll
                for (int q = 0; q < 4; ++q) s += dot4(wg[q], hp[q]);
                glog[bb][c] = s;
                float4 ga = *(const float4*)&glog[bb][0];
                float4 gb = *(const float4*)&glog[bb][4];
                float mx = fmaxf(fmaxf(fmaxf(ga.x, ga.y), fmaxf(ga.z, ga.w)),
                                 fmaxf(fmaxf(gb.x, gb.y), fmaxf(gb.z, gb.w)));
                float sum = __expf(ga.x - mx) + __expf(ga.y - mx) + __expf(ga.z - mx) + __expf(ga.w - mx)
                          + __expf(gb.x - mx) + __expf(gb.y - mx) + __expf(gb.z - mx) + __expf(gb.w - mx);
                float p = __expf(s - mx) / sum;
                float th = thS[bb];
                gateS[bb][c] = p * th + gateS[bb][c] * (1.f - th);
            }
            // combine -> ehH + ecS
            {
                int bb = j >> 4, h = j & 15;
                float se = 0.f, sc = 0.f;
                #pragma unroll
                for (int c = 0; c < 8; ++c) {
                    float g = gateS[bb][c];
                    se = fmaf(g, nhS[c][bb][h], se);
                    sc = fmaf(g, ncS[c][bb][h], sc);
                }
                ehH[bb][h] = (_Float16)se;
                ecS[bb][h] = sc;
            }
            // pred + output + next x slot
            if (j < NB) {
                float s = 0.f;
                #pragma unroll
                for (int c = 0; c < 8; ++c) s = fmaf(gateS[j][c], oS[j][c], s);
                predS[j] = s;
                out[(b0 + j) * S_LEN + t] = s;
                ehH[j][16] = (_Float16)((t + 1 < S_LEN) ? xS[j][t + 1] : 0.f);
            }
        }
        __syncthreads();   // B3
    }
}

extern "C" void kernel_launch(void* const* d_in, const int* in_sizes, int n_in,
                              void* d_out, int out_size, void* d_ws, size_t ws_size,
                              hipStream_t stream) {
    const float* xp    = (const float*)d_in[0];
    const float* pred0 = (const float*)d_in[1];
    const float* gate0 = (const float*)d_in[2];
    const float* W_ih  = (const float*)d_in[3];
    const float* W_hh  = (const float*)d_in[4];
    const float* b_ih  = (const float*)d_in[5];
    const float* b_hh  = (const float*)d_in[6];
    const float* W_o   = (const float*)d_in[7];
    const float* b_o   = (const float*)d_in[8];
    const float* W1    = (const float*)d_in[9];
    const float* b1    = (const float*)d_in[10];
    const float* W2    = (const float*)d_in[11];
    const float* b2    = (const float*)d_in[12];
    const float* Wg    = (const float*)d_in[13];
    const float* bg    = (const float*)d_in[14];
    const float* Wa_ih = (const float*)d_in[15];
    const float* Wa_hh = (const float*)d_in[16];
    const float* ba_ih = (const float*)d_in[17];
    const float* ba_hh = (const float*)d_in[18];
    _Float16* W1F  = (_Float16*)d_ws;                // 163840 f16
    _Float16* WAF  = W1F + 163840;                   // 16384
    _Float16* W2F  = WAF + 16384;                    // 1024
    _Float16* WAGF = W2F + 1024;                     // 4096

    prep_w<<<(163840 + 16384 + 1024 + 4096 + 255) / 256, 256, 0, stream>>>(
        W1, W_hh, W_ih, b_ih, b_hh, W2, Wa_ih, Wa_hh, W1F, WAF, W2F, WAGF);
    mmoe_kernel<<<512 / NB, NTHR, 0, stream>>>(
        xp, pred0, gate0, W_ih, W_hh, b_ih, b_hh, W_o, b_o,
        W1, b1, W2, b2, Wg, bg, Wa_ih, Wa_hh, ba_ih, ba_hh,
        W1F, WAF, W2F, WAGF, (float*)d_out);
}